// Round 1
// baseline (406.309 us; speedup 1.0000x reference)
//
#include <hip/hip_runtime.h>
#include <math.h>

#define D_DIM 256
#define HW 16384
#define C 19
#define N_PX 131072
#define EPS 1e-8f

// ws layout (float offsets)
#define OFF_CNT     0        // 19
#define OFF_DIFF    20       // 1
#define OFF_SIMTOT  21       // 1
#define OFF_NCEN    32       // 19
#define OFF_SUMS    64       // 4864
#define OFF_CENTERS 4928     // 4864
#define OFF_PDOT    16384    // 131072
#define OFF_PNF     147456   // 131072
#define WS_FLOATS   278528   // ~1.06 MB

// ---------- K0: zero the workspace region we use (ws is re-poisoned to 0xAA each launch) ----------
__global__ void k0_zero(float* __restrict__ ws) {
    int i = blockIdx.x * blockDim.x + threadIdx.x;
    int stride = gridDim.x * blockDim.x;
    for (; i < WS_FLOATS; i += stride) ws[i] = 0.f;
}

// ---------- K1: per-class counts + per-class sums over D ----------
// grid (128, 8): x = 1024-pixel chunk, y = 32-wide d chunk. 256 threads, 4 px/thread (float4 along w).
__global__ __launch_bounds__(256) void k1_sums(const float* __restrict__ in,
                                               const int* __restrict__ tgt,
                                               float* __restrict__ ws) {
    __shared__ float s_sum[C * 33];   // pad 33: bank = (c + dd) % 32 -> classes spread across banks
    __shared__ float s_cnt[C];
    const int tid = threadIdx.x;
    for (int i = tid; i < C * 33; i += 256) s_sum[i] = 0.f;
    if (tid < C) s_cnt[tid] = 0.f;
    __syncthreads();

    const int px0 = blockIdx.x << 10;           // 1024 px per block (stays within one b: HW=16384)
    const int b   = px0 >> 14;
    const int hw  = (px0 & (HW - 1)) + (tid << 2);
    const int d0  = blockIdx.y << 5;
    const int p   = px0 + (tid << 2);

    const int l0 = tgt[p], l1 = tgt[p + 1], l2 = tgt[p + 2], l3 = tgt[p + 3];
    if (blockIdx.y == 0) {
        atomicAdd(&s_cnt[l0], 1.f); atomicAdd(&s_cnt[l1], 1.f);
        atomicAdd(&s_cnt[l2], 1.f); atomicAdd(&s_cnt[l3], 1.f);
    }

    const float* base = in + (((size_t)(b * D_DIM + d0)) << 14) + hw;
    for (int dd = 0; dd < 32; ++dd) {
        float4 v = *(const float4*)(base + ((size_t)dd << 14));
        atomicAdd(&s_sum[l0 * 33 + dd], v.x);
        atomicAdd(&s_sum[l1 * 33 + dd], v.y);
        atomicAdd(&s_sum[l2 * 33 + dd], v.z);
        atomicAdd(&s_sum[l3 * 33 + dd], v.w);
    }
    __syncthreads();

    for (int i = tid; i < C * 32; i += 256) {
        int c = i >> 5, dd = i & 31;
        atomicAdd(&ws[OFF_SUMS + c * D_DIM + d0 + dd], s_sum[c * 33 + dd]);
    }
    if (blockIdx.y == 0 && tid < C) atomicAdd(&ws[OFF_CNT + tid], s_cnt[tid]);
}

// ---------- K2: centers, center norms, diff_loss (single block) ----------
__global__ __launch_bounds__(384) void k2_centers(float* __restrict__ ws) {
    __shared__ float s_cen[C * 257];  // padded: bank = (c + d) % 32
    __shared__ float s_nsq[C];
    __shared__ float s_ncen[C];
    __shared__ float s_diff;
    const int tid = threadIdx.x;
    if (tid < C) s_nsq[tid] = 0.f;
    if (tid == 0) s_diff = 0.f;
    __syncthreads();

    for (int i = tid; i < C * D_DIM; i += 384) {
        int c = i >> 8, d = i & 255;
        float cnt = ws[OFF_CNT + c];
        float cen = ws[OFF_SUMS + i] / fmaxf(cnt, 1.f);
        ws[OFF_CENTERS + i] = cen;
        s_cen[c * 257 + d]  = cen;
        atomicAdd(&s_nsq[c], cen * cen);
    }
    __syncthreads();
    if (tid < C) {
        float n = sqrtf(s_nsq[tid]);
        s_ncen[tid] = n;
        ws[OFF_NCEN + tid] = n;
    }
    __syncthreads();
    if (tid < C * C) {
        int i = tid / C, j = tid % C;
        float dot = 0.f;
        for (int d = 0; d < D_DIM; ++d)
            dot += s_cen[i * 257 + d] * s_cen[j * 257 + d];
        float S   = dot / fmaxf(s_ncen[i] * s_ncen[j], EPS);
        float val = (i == j) ? (1.f - S) : fmaxf(S, 0.f);
        if (ws[OFF_CNT + i] > 0.f)
            atomicAdd(&s_diff, val * (1.f / (float)C));
    }
    __syncthreads();
    if (tid == 0) ws[OFF_DIFF] = s_diff;
}

// ---------- K3a: per-pixel partial dot(feat, center[label]) and ||feat||^2, d-chunked ----------
__global__ __launch_bounds__(256) void k3a_dot(const float* __restrict__ in,
                                               const int* __restrict__ tgt,
                                               float* __restrict__ ws) {
    __shared__ float s_cen[C * 33];
    const int tid = threadIdx.x;
    const int d0  = blockIdx.y << 5;
    for (int i = tid; i < C * 32; i += 256) {
        int c = i >> 5, dd = i & 31;
        s_cen[c * 33 + dd] = ws[OFF_CENTERS + c * D_DIM + d0 + dd];
    }
    __syncthreads();

    const int px0 = blockIdx.x << 10;
    const int b   = px0 >> 14;
    const int hw  = (px0 & (HW - 1)) + (tid << 2);
    const int p   = px0 + (tid << 2);
    const int l0 = tgt[p], l1 = tgt[p + 1], l2 = tgt[p + 2], l3 = tgt[p + 3];

    const float* base = in + (((size_t)(b * D_DIM + d0)) << 14) + hw;
    float dt0 = 0.f, dt1 = 0.f, dt2 = 0.f, dt3 = 0.f;
    float nf0 = 0.f, nf1 = 0.f, nf2 = 0.f, nf3 = 0.f;
    for (int dd = 0; dd < 32; ++dd) {
        float4 v = *(const float4*)(base + ((size_t)dd << 14));
        dt0 += v.x * s_cen[l0 * 33 + dd]; nf0 += v.x * v.x;
        dt1 += v.y * s_cen[l1 * 33 + dd]; nf1 += v.y * v.y;
        dt2 += v.z * s_cen[l2 * 33 + dd]; nf2 += v.z * v.z;
        dt3 += v.w * s_cen[l3 * 33 + dd]; nf3 += v.w * v.w;
    }
    atomicAdd(&ws[OFF_PDOT + p],     dt0);
    atomicAdd(&ws[OFF_PDOT + p + 1], dt1);
    atomicAdd(&ws[OFF_PDOT + p + 2], dt2);
    atomicAdd(&ws[OFF_PDOT + p + 3], dt3);
    atomicAdd(&ws[OFF_PNF + p],      nf0);
    atomicAdd(&ws[OFF_PNF + p + 1],  nf1);
    atomicAdd(&ws[OFF_PNF + p + 2],  nf2);
    atomicAdd(&ws[OFF_PNF + p + 3],  nf3);
}

// ---------- K3b: per-pixel (1 - cos)/count, reduced into SIMTOT ----------
__global__ __launch_bounds__(256) void k3b_sim(const int* __restrict__ tgt,
                                               float* __restrict__ ws) {
    const int p = blockIdx.x * 256 + threadIdx.x;
    const int l = tgt[p];
    const float dot = ws[OFF_PDOT + p];
    const float nf  = ws[OFF_PNF + p];
    const float nc  = ws[OFF_NCEN + l];
    const float cnt = ws[OFF_CNT + l];
    const float cosv = dot / fmaxf(sqrtf(nf) * nc, EPS);
    float contrib = (1.f - cosv) / fmaxf(cnt, 1.f);
    #pragma unroll
    for (int off = 32; off > 0; off >>= 1)
        contrib += __shfl_down(contrib, off, 64);
    if ((threadIdx.x & 63) == 0)
        atomicAdd(&ws[OFF_SIMTOT], contrib);
}

// ---------- K4: final ----------
__global__ void k4_final(const float* __restrict__ ws, float* __restrict__ out) {
    if (threadIdx.x == 0 && blockIdx.x == 0)
        out[0] = ws[OFF_SIMTOT] + ws[OFF_DIFF];
}

extern "C" void kernel_launch(void* const* d_in, const int* in_sizes, int n_in,
                              void* d_out, int out_size, void* d_ws, size_t ws_size,
                              hipStream_t stream) {
    const float* in  = (const float*)d_in[0];
    const int*   tgt = (const int*)d_in[1];
    float* out = (float*)d_out;
    float* ws  = (float*)d_ws;

    k0_zero<<<512, 256, 0, stream>>>(ws);
    k1_sums<<<dim3(128, 8), 256, 0, stream>>>(in, tgt, ws);
    k2_centers<<<1, 384, 0, stream>>>(ws);
    k3a_dot<<<dim3(128, 8), 256, 0, stream>>>(in, tgt, ws);
    k3b_sim<<<512, 256, 0, stream>>>(tgt, ws);
    k4_final<<<1, 64, 0, stream>>>(ws, out);
}

// Round 2
// 236.620 us; speedup vs baseline: 1.7171x; 1.7171x over previous
//
#include <hip/hip_runtime.h>
#include <math.h>

#define D_DIM 256
#define HW 16384
#define C 19
#define N_PX 131072
#define EPS 1e-8f

#define S_SUM 1048576.0f   // 2^20 fixed point for class sums
#define IS_SUM (1.0f/1048576.0f)
#define S_NF  65536.0f     // 2^16 for ||f||^2 partials
#define IS_NF (1.0f/65536.0f)
#define S_DOT 65536.0f     // 2^16 for dot partials
#define IS_DOT (1.0f/65536.0f)

// ws layout in 4-byte words
#define OFF_SUMS_I   0        // int[4864]   class sums, fixed-point
#define OFF_CNT_I    5120     // int[19]     class counts
#define OFF_NCEN_F   5632     // float[19]   center norms
#define OFF_CNT_F    6144     // float[19]   counts as float
#define OFF_DIFF_F   6656     // float[1]    diff_loss
#define OFF_CEN_F    8192     // float[4864] centers
#define OFF_NF_I     16384    // int[131072] per-pixel ||f||^2 fixed-point
#define OFF_DOT_I    147456   // int[131072] per-pixel dot fixed-point
#define OFF_WSUM_F   278528   // float[2048] per-wave sim partials
#define WS_WORDS     280576   // ~1.12 MB

// ---------- K0: zero used workspace ----------
__global__ void k0_zero(int* __restrict__ ws) {
    int i = blockIdx.x * blockDim.x + threadIdx.x;
    int stride = gridDim.x * blockDim.x;
    for (; i < WS_WORDS; i += stride) ws[i] = 0;
}

// ---------- K1: class counts + class sums (int LDS atomics) + per-pixel ||f||^2 partials ----------
// grid (128, 8): x = 1024-px chunk, y = 32-wide d chunk. 4 px/thread via float4.
__global__ __launch_bounds__(256) void k1_sums(const float* __restrict__ in,
                                               const int* __restrict__ tgt,
                                               int* __restrict__ wsi) {
    __shared__ int s_sum[C * 33];  // pad 33 -> class c, dd maps to bank (c+dd)%32
    __shared__ int s_cnt[C];
    const int tid = threadIdx.x;
    for (int i = tid; i < C * 33; i += 256) s_sum[i] = 0;
    if (tid < C) s_cnt[tid] = 0;
    __syncthreads();

    const int px0 = blockIdx.x << 10;
    const int b   = px0 >> 14;
    const int hw  = (px0 & (HW - 1)) + (tid << 2);
    const int d0  = blockIdx.y << 5;
    const int p   = px0 + (tid << 2);
    const int l0 = tgt[p], l1 = tgt[p + 1], l2 = tgt[p + 2], l3 = tgt[p + 3];
    if (blockIdx.y == 0) {
        atomicAdd(&s_cnt[l0], 1); atomicAdd(&s_cnt[l1], 1);
        atomicAdd(&s_cnt[l2], 1); atomicAdd(&s_cnt[l3], 1);
    }

    const float* base = in + (((size_t)(b * D_DIM + d0)) << 14) + hw;
    float nf0 = 0.f, nf1 = 0.f, nf2 = 0.f, nf3 = 0.f;
    #pragma unroll
    for (int g = 0; g < 4; ++g) {
        float4 v[8];                       // 8 loads in flight per group
        #pragma unroll
        for (int j = 0; j < 8; ++j)
            v[j] = *(const float4*)(base + ((size_t)(g * 8 + j) << 14));
        #pragma unroll
        for (int j = 0; j < 8; ++j) {
            const int dd = g * 8 + j;
            nf0 += v[j].x * v[j].x; nf1 += v[j].y * v[j].y;
            nf2 += v[j].z * v[j].z; nf3 += v[j].w * v[j].w;
            atomicAdd(&s_sum[l0 * 33 + dd], __float2int_rn(v[j].x * S_SUM));
            atomicAdd(&s_sum[l1 * 33 + dd], __float2int_rn(v[j].y * S_SUM));
            atomicAdd(&s_sum[l2 * 33 + dd], __float2int_rn(v[j].z * S_SUM));
            atomicAdd(&s_sum[l3 * 33 + dd], __float2int_rn(v[j].w * S_SUM));
        }
    }
    // per-pixel ||f||^2 partial: native int global atomic (8-way contention across y)
    atomicAdd(&wsi[OFF_NF_I + p],     __float2int_rn(nf0 * S_NF));
    atomicAdd(&wsi[OFF_NF_I + p + 1], __float2int_rn(nf1 * S_NF));
    atomicAdd(&wsi[OFF_NF_I + p + 2], __float2int_rn(nf2 * S_NF));
    atomicAdd(&wsi[OFF_NF_I + p + 3], __float2int_rn(nf3 * S_NF));

    __syncthreads();
    for (int i = tid; i < C * 32; i += 256) {
        int c = i >> 5, dd = i & 31;
        atomicAdd(&wsi[OFF_SUMS_I + c * D_DIM + d0 + dd], s_sum[c * 33 + dd]);
    }
    if (blockIdx.y == 0 && tid < C) atomicAdd(&wsi[OFF_CNT_I + tid], s_cnt[tid]);
}

// ---------- K2: centers, norms, Gram, diff_loss (1 block, atomic-free) ----------
__global__ __launch_bounds__(384) void k2_centers(int* __restrict__ wsi) {
    float* wsf = (float*)wsi;
    __shared__ float s_cen[C * 257];
    __shared__ float s_ncen[C];
    __shared__ float s_pair[C * C];
    __shared__ float s_red[C];
    const int tid = threadIdx.x;

    for (int i = tid; i < C * D_DIM; i += 384) {
        int c = i >> 8, d = i & 255;
        float cnt = (float)wsi[OFF_CNT_I + c];
        float cen = ((float)wsi[OFF_SUMS_I + i]) * IS_SUM / fmaxf(cnt, 1.f);
        wsf[OFF_CEN_F + i] = cen;
        s_cen[c * 257 + d] = cen;
    }
    __syncthreads();
    if (tid < C) {
        float nsq = 0.f;
        for (int d = 0; d < D_DIM; ++d) {
            float x = s_cen[tid * 257 + d];
            nsq += x * x;
        }
        float n = sqrtf(nsq);
        s_ncen[tid] = n;
        wsf[OFF_NCEN_F + tid] = n;
        wsf[OFF_CNT_F + tid]  = (float)wsi[OFF_CNT_I + tid];
    }
    __syncthreads();
    if (tid < C * C) {
        int i = tid / C, j = tid % C;
        float dot = 0.f;
        for (int d = 0; d < D_DIM; ++d)
            dot += s_cen[i * 257 + d] * s_cen[j * 257 + d];
        float S = dot / fmaxf(s_ncen[i] * s_ncen[j], EPS);
        s_pair[tid] = (i == j) ? (1.f - S) : fmaxf(S, 0.f);
    }
    __syncthreads();
    if (tid < C) {
        float row = 0.f;
        for (int j = 0; j < C; ++j) row += s_pair[tid * C + j];
        s_red[tid] = (wsi[OFF_CNT_I + tid] > 0) ? (row / (float)C) : 0.f;
    }
    __syncthreads();
    if (tid == 0) {
        float diff = 0.f;
        for (int i = 0; i < C; ++i) diff += s_red[i];
        wsf[OFF_DIFF_F] = diff;
    }
}

// ---------- K3: per-pixel dot(feat, center[label]) partials, d-chunked ----------
__global__ __launch_bounds__(256) void k3_dot(const float* __restrict__ in,
                                              const int* __restrict__ tgt,
                                              int* __restrict__ wsi) {
    const float* wsf = (const float*)wsi;
    __shared__ float s_cen[C * 33];
    const int tid = threadIdx.x;
    const int d0  = blockIdx.y << 5;
    for (int i = tid; i < C * 32; i += 256) {
        int c = i >> 5, dd = i & 31;
        s_cen[c * 33 + dd] = wsf[OFF_CEN_F + c * D_DIM + d0 + dd];
    }
    __syncthreads();

    const int px0 = blockIdx.x << 10;
    const int b   = px0 >> 14;
    const int hw  = (px0 & (HW - 1)) + (tid << 2);
    const int p   = px0 + (tid << 2);
    const int l0 = tgt[p], l1 = tgt[p + 1], l2 = tgt[p + 2], l3 = tgt[p + 3];

    const float* base = in + (((size_t)(b * D_DIM + d0)) << 14) + hw;
    float dt0 = 0.f, dt1 = 0.f, dt2 = 0.f, dt3 = 0.f;
    #pragma unroll
    for (int g = 0; g < 4; ++g) {
        float4 v[8];
        #pragma unroll
        for (int j = 0; j < 8; ++j)
            v[j] = *(const float4*)(base + ((size_t)(g * 8 + j) << 14));
        #pragma unroll
        for (int j = 0; j < 8; ++j) {
            const int dd = g * 8 + j;
            dt0 += v[j].x * s_cen[l0 * 33 + dd];  // same-label lanes broadcast; distinct labels distinct banks
            dt1 += v[j].y * s_cen[l1 * 33 + dd];
            dt2 += v[j].z * s_cen[l2 * 33 + dd];
            dt3 += v[j].w * s_cen[l3 * 33 + dd];
        }
    }
    atomicAdd(&wsi[OFF_DOT_I + p],     __float2int_rn(dt0 * S_DOT));
    atomicAdd(&wsi[OFF_DOT_I + p + 1], __float2int_rn(dt1 * S_DOT));
    atomicAdd(&wsi[OFF_DOT_I + p + 2], __float2int_rn(dt2 * S_DOT));
    atomicAdd(&wsi[OFF_DOT_I + p + 3], __float2int_rn(dt3 * S_DOT));
}

// ---------- K3b: per-pixel (1-cos)/count -> per-wave partials (no atomics) ----------
__global__ __launch_bounds__(256) void k3b_sim(const int* __restrict__ tgt,
                                               int* __restrict__ wsi) {
    float* wsf = (float*)wsi;
    const int p = blockIdx.x * 256 + threadIdx.x;
    const int l = tgt[p];
    const float dot = (float)wsi[OFF_DOT_I + p] * IS_DOT;
    const float nf  = (float)wsi[OFF_NF_I + p]  * IS_NF;
    const float nc  = wsf[OFF_NCEN_F + l];
    const float cnt = wsf[OFF_CNT_F + l];
    const float cosv = dot / fmaxf(sqrtf(nf) * nc, EPS);
    float contrib = (1.f - cosv) / fmaxf(cnt, 1.f);
    #pragma unroll
    for (int off = 32; off > 0; off >>= 1)
        contrib += __shfl_down(contrib, off, 64);
    if ((threadIdx.x & 63) == 0)
        wsf[OFF_WSUM_F + blockIdx.x * 4 + (threadIdx.x >> 6)] = contrib;
}

// ---------- K4: final reduce (1 block) ----------
__global__ __launch_bounds__(256) void k4_final(const int* __restrict__ wsi,
                                                float* __restrict__ out) {
    const float* wsf = (const float*)wsi;
    __shared__ float s_w[4];
    float s = 0.f;
    for (int k = threadIdx.x; k < 2048; k += 256) s += wsf[OFF_WSUM_F + k];
    #pragma unroll
    for (int off = 32; off > 0; off >>= 1)
        s += __shfl_down(s, off, 64);
    if ((threadIdx.x & 63) == 0) s_w[threadIdx.x >> 6] = s;
    __syncthreads();
    if (threadIdx.x == 0)
        out[0] = s_w[0] + s_w[1] + s_w[2] + s_w[3] + wsf[OFF_DIFF_F];
}

extern "C" void kernel_launch(void* const* d_in, const int* in_sizes, int n_in,
                              void* d_out, int out_size, void* d_ws, size_t ws_size,
                              hipStream_t stream) {
    const float* in  = (const float*)d_in[0];
    const int*   tgt = (const int*)d_in[1];
    float* out = (float*)d_out;
    int*   wsi = (int*)d_ws;

    k0_zero<<<512, 256, 0, stream>>>(wsi);
    k1_sums<<<dim3(128, 8), 256, 0, stream>>>(in, tgt, wsi);
    k2_centers<<<1, 384, 0, stream>>>(wsi);
    k3_dot<<<dim3(128, 8), 256, 0, stream>>>(in, tgt, wsi);
    k3b_sim<<<512, 256, 0, stream>>>(tgt, wsi);
    k4_final<<<1, 256, 0, stream>>>(wsi, out);
}

// Round 3
// 233.597 us; speedup vs baseline: 1.7394x; 1.0129x over previous
//
#include <hip/hip_runtime.h>
#include <math.h>

#define D_DIM 256
#define HW 16384
#define C 19
#define N_PX 131072
#define EPS 1e-8f

#define S_SUM 1048576.0f   // 2^20 fixed point for class sums
#define IS_SUM (1.0f/1048576.0f)

// ws layout in 4-byte words
#define OFF_SUMS_I   0        // int[4864]   class sums, fixed-point
#define OFF_CNT_I    4864     // int[19]     class counts
#define OFF_DIFF_F   4883     // float[1]    diff_loss
#define OFF_NCEN_F   4884     // float[19]   center norms
#define OFF_ICNT_F   4903     // float[19]   1/max(cnt,1)
#define OFF_CEN_F    4928     // float[4864] centers (byte off 19712, 16B aligned)
#define OFF_WSUM_F   9792     // float[1024] per-wave sim partials
#define WS_ZERO      4883     // only SUMS_I + CNT_I need zeroing

// ---------- K0: zero class accumulators ----------
__global__ void k0_zero(int* __restrict__ ws) {
    int i = blockIdx.x * blockDim.x + threadIdx.x;
    if (i < WS_ZERO) ws[i] = 0;
}

// ---------- K1: class counts + class sums (int LDS atomics) ----------
// grid (256, 8): x = 512-px chunk, y = 32-wide d chunk. 2 px/thread via float2.
__global__ __launch_bounds__(256) void k1_sums(const float* __restrict__ in,
                                               const int* __restrict__ tgt,
                                               int* __restrict__ wsi) {
    __shared__ int s_sum[C * 33];  // bank = (c + dd) % 32 -> classes spread across banks
    __shared__ int s_cnt[C];
    const int tid = threadIdx.x;
    for (int i = tid; i < C * 33; i += 256) s_sum[i] = 0;
    if (tid < C) s_cnt[tid] = 0;
    __syncthreads();

    const int px0 = blockIdx.x << 9;           // 512 px per block
    const int b   = px0 >> 14;
    const int hw  = (px0 & (HW - 1)) + (tid << 1);
    const int d0  = blockIdx.y << 5;
    const int p   = px0 + (tid << 1);
    const int la = tgt[p], lb = tgt[p + 1];
    if (blockIdx.y == 0) {
        atomicAdd(&s_cnt[la], 1); atomicAdd(&s_cnt[lb], 1);
    }

    const float* base = in + (((size_t)(b * D_DIM + d0)) << 14) + hw;
    #pragma unroll
    for (int g = 0; g < 4; ++g) {
        float2 v[8];                       // 8 loads in flight
        #pragma unroll
        for (int j = 0; j < 8; ++j)
            v[j] = *(const float2*)(base + ((size_t)(g * 8 + j) << 14));
        #pragma unroll
        for (int j = 0; j < 8; ++j) {
            const int dd = g * 8 + j;
            atomicAdd(&s_sum[la * 33 + dd], __float2int_rn(v[j].x * S_SUM));
            atomicAdd(&s_sum[lb * 33 + dd], __float2int_rn(v[j].y * S_SUM));
        }
    }
    __syncthreads();
    for (int i = tid; i < C * 32; i += 256) {
        int c = i >> 5, dd = i & 31;
        atomicAdd(&wsi[OFF_SUMS_I + c * D_DIM + d0 + dd], s_sum[c * 33 + dd]);
    }
    if (blockIdx.y == 0 && tid < C) atomicAdd(&wsi[OFF_CNT_I + tid], s_cnt[tid]);
}

// ---------- K2: centers, norms, Gram, diff_loss (1 block, atomic-free) ----------
__global__ __launch_bounds__(384) void k2_centers(int* __restrict__ wsi) {
    float* wsf = (float*)wsi;
    __shared__ float s_cen[C * 257];
    __shared__ float s_ncen[C];
    __shared__ float s_pair[C * C];
    __shared__ float s_red[C];
    const int tid = threadIdx.x;

    for (int i = tid; i < C * D_DIM; i += 384) {
        int c = i >> 8, d = i & 255;
        float cnt = (float)wsi[OFF_CNT_I + c];
        float cen = ((float)wsi[OFF_SUMS_I + i]) * IS_SUM / fmaxf(cnt, 1.f);
        wsf[OFF_CEN_F + i] = cen;
        s_cen[c * 257 + d] = cen;
    }
    __syncthreads();
    if (tid < C) {
        float nsq = 0.f;
        for (int d = 0; d < D_DIM; ++d) {
            float x = s_cen[tid * 257 + d];
            nsq += x * x;
        }
        float n = sqrtf(nsq);
        s_ncen[tid] = n;
        wsf[OFF_NCEN_F + tid] = n;
        float cnt = (float)wsi[OFF_CNT_I + tid];
        wsf[OFF_ICNT_F + tid] = 1.f / fmaxf(cnt, 1.f);
    }
    __syncthreads();
    if (tid < C * C) {
        int i = tid / C, j = tid % C;
        float dot = 0.f;
        for (int d = 0; d < D_DIM; ++d)
            dot += s_cen[i * 257 + d] * s_cen[j * 257 + d];
        float S = dot / fmaxf(s_ncen[i] * s_ncen[j], EPS);
        s_pair[tid] = (i == j) ? (1.f - S) : fmaxf(S, 0.f);
    }
    __syncthreads();
    if (tid < C) {
        float row = 0.f;
        for (int j = 0; j < C; ++j) row += s_pair[tid * C + j];
        s_red[tid] = (wsi[OFF_CNT_I + tid] > 0) ? (row / (float)C) : 0.f;
    }
    __syncthreads();
    if (tid == 0) {
        float diff = 0.f;
        for (int i = 0; i < C; ++i) diff += s_red[i];
        wsf[OFF_DIFF_F] = diff;
    }
}

// ---------- K3: fused pass 2 — full-D dot + ||f||^2 + per-pixel sim, no atomics ----------
// grid 256: each block owns 512 px; 2 px/thread (float2); loops all 256 d.
__global__ __launch_bounds__(256) void k3_sim(const float* __restrict__ in,
                                              const int* __restrict__ tgt,
                                              int* __restrict__ wsi) {
    float* wsf = (float*)wsi;
    __shared__ float4 s_cen4[C * 65];  // row stride 260 floats: bank=(4c+dd)%32, <=3-way; 16B aligned
    __shared__ float s_ncen[C];
    __shared__ float s_icnt[C];
    const int tid = threadIdx.x;
    const float4* cen_g = (const float4*)(wsf + OFF_CEN_F);
    for (int i = tid; i < C * 64; i += 256) {
        int c = i >> 6, g = i & 63;
        s_cen4[c * 65 + g] = cen_g[c * 64 + g];
    }
    if (tid < C) {
        s_ncen[tid] = wsf[OFF_NCEN_F + tid];
        s_icnt[tid] = wsf[OFF_ICNT_F + tid];
    }
    __syncthreads();

    const int px0 = blockIdx.x << 9;
    const int b   = px0 >> 14;
    const int hw  = (px0 & (HW - 1)) + (tid << 1);
    const int p   = px0 + (tid << 1);
    const int la = tgt[p], lb = tgt[p + 1];
    const float4* ca = &s_cen4[la * 65];
    const float4* cb = &s_cen4[lb * 65];

    const float* base = in + (((size_t)(b * D_DIM)) << 14) + hw;
    float dta = 0.f, dtb = 0.f, nfa = 0.f, nfb = 0.f;
    #pragma unroll 4
    for (int g = 0; g < 32; ++g) {       // 8 d's per group
        float2 v[8];
        #pragma unroll
        for (int j = 0; j < 8; ++j)
            v[j] = *(const float2*)(base + ((size_t)(g * 8 + j) << 14));
        float4 a0 = ca[g * 2], a1 = ca[g * 2 + 1];
        float4 b0 = cb[g * 2], b1 = cb[g * 2 + 1];
        dta += v[0].x * a0.x + v[1].x * a0.y + v[2].x * a0.z + v[3].x * a0.w
             + v[4].x * a1.x + v[5].x * a1.y + v[6].x * a1.z + v[7].x * a1.w;
        dtb += v[0].y * b0.x + v[1].y * b0.y + v[2].y * b0.z + v[3].y * b0.w
             + v[4].y * b1.x + v[5].y * b1.y + v[6].y * b1.z + v[7].y * b1.w;
        nfa += v[0].x * v[0].x + v[1].x * v[1].x + v[2].x * v[2].x + v[3].x * v[3].x
             + v[4].x * v[4].x + v[5].x * v[5].x + v[6].x * v[6].x + v[7].x * v[7].x;
        nfb += v[0].y * v[0].y + v[1].y * v[1].y + v[2].y * v[2].y + v[3].y * v[3].y
             + v[4].y * v[4].y + v[5].y * v[5].y + v[6].y * v[6].y + v[7].y * v[7].y;
    }

    const float cosa = dta / fmaxf(sqrtf(nfa) * s_ncen[la], EPS);
    const float cosb = dtb / fmaxf(sqrtf(nfb) * s_ncen[lb], EPS);
    float contrib = (1.f - cosa) * s_icnt[la] + (1.f - cosb) * s_icnt[lb];
    #pragma unroll
    for (int off = 32; off > 0; off >>= 1)
        contrib += __shfl_down(contrib, off, 64);
    if ((tid & 63) == 0)
        wsf[OFF_WSUM_F + blockIdx.x * 4 + (tid >> 6)] = contrib;
}

// ---------- K4: final reduce (1 block) ----------
__global__ __launch_bounds__(256) void k4_final(const int* __restrict__ wsi,
                                                float* __restrict__ out) {
    const float* wsf = (const float*)wsi;
    __shared__ float s_w[4];
    float s = 0.f;
    for (int k = threadIdx.x; k < 1024; k += 256) s += wsf[OFF_WSUM_F + k];
    #pragma unroll
    for (int off = 32; off > 0; off >>= 1)
        s += __shfl_down(s, off, 64);
    if ((threadIdx.x & 63) == 0) s_w[threadIdx.x >> 6] = s;
    __syncthreads();
    if (threadIdx.x == 0)
        out[0] = s_w[0] + s_w[1] + s_w[2] + s_w[3] + wsf[OFF_DIFF_F];
}

extern "C" void kernel_launch(void* const* d_in, const int* in_sizes, int n_in,
                              void* d_out, int out_size, void* d_ws, size_t ws_size,
                              hipStream_t stream) {
    const float* in  = (const float*)d_in[0];
    const int*   tgt = (const int*)d_in[1];
    float* out = (float*)d_out;
    int*   wsi = (int*)d_ws;

    k0_zero<<<20, 256, 0, stream>>>(wsi);
    k1_sums<<<dim3(256, 8), 256, 0, stream>>>(in, tgt, wsi);
    k2_centers<<<1, 384, 0, stream>>>(wsi);
    k3_sim<<<256, 256, 0, stream>>>(in, tgt, wsi);
    k4_final<<<1, 256, 0, stream>>>(wsi, out);
}